// Round 3
// baseline (450.496 us; speedup 1.0000x reference)
//
#include <hip/hip_runtime.h>

// Problem constants (from reference): N_T=5, 32x32 grid, N=1024, batch=4.
#define NT   5
#define NY   32
#define NX   32
#define NN   1024          // N = NY*NX
#define QDIM 5120          // NT * NN
#define NB   4
#define G    8             // rows per block in band builder

typedef float vfloat4 __attribute__((ext_vector_type(4)));

// Canonical stencil offset order (matches reference's offs list):
// 0:(0,0) 1:(0,1) 2:(0,-1) 3:(1,0) 4:(-1,0) 5:(1,1) 6:(1,-1) 7:(-1,1) 8:(-1,-1)
__device__ const int c_oy[9] = {0, 0, 0, 1, -1, 1, 1, -1, -1};
__device__ const int c_ox[9] = {0, 1, -1, 0, 0, 1, -1, 1, -1};

// Stencil coefficients of M = I + A for node n, time t, batch b.
__device__ __forceinline__ void stencil9(const float* __restrict__ kap,
                                         const float* __restrict__ m,
                                         const float* __restrict__ H,
                                         int b, int t, int n, float s[9]) {
    // Layouts: kappa (NB,1,NN,NT); m (NB,2,NN,NT); H (NB,2,2,NN,NT)
    float k   = kap[((size_t)b * NN + n) * NT + t];
    float mx  = m[(((size_t)b * 2 + 0) * NN + n) * NT + t];
    float my  = m[(((size_t)b * 2 + 1) * NN + n) * NT + t];
    float H11 = H[((((size_t)b * 2 + 0) * 2 + 0) * NN + n) * NT + t];
    float H01 = H[((((size_t)b * 2 + 0) * 2 + 1) * NN + n) * NT + t];
    float H10 = H[((((size_t)b * 2 + 1) * 2 + 0) * NN + n) * NT + t];
    float H22 = H[((((size_t)b * 2 + 1) * 2 + 1) * NN + n) * NT + t];
    float cc = 0.25f * (H01 + H10);                  // H12/(2 DX DY), DX=DY=1
    s[0] = 1.0f + k * k + 2.0f * H11 + 2.0f * H22;   // diag of M = 1 + c0
    s[1] =  0.5f * mx - H11;    // (0,+1)
    s[2] = -0.5f * mx - H11;    // (0,-1)
    s[3] =  0.5f * my - H22;    // (+1,0)
    s[4] = -0.5f * my - H22;    // (-1,0)
    s[5] = -cc;                 // (+1,+1)
    s[6] =  cc;                 // (+1,-1)
    s[7] =  cc;                 // (-1,+1)
    s[8] = -cc;                 // (-1,-1)
    int y = n >> 5, x = n & 31;
    if (x == NX - 1) { s[1] = 0.f; s[5] = 0.f; s[7] = 0.f; }
    if (x == 0)      { s[2] = 0.f; s[6] = 0.f; s[8] = 0.f; }
    if (y == NY - 1) { s[3] = 0.f; s[5] = 0.f; s[6] = 0.f; }
    if (y == 0)      { s[4] = 0.f; s[7] = 0.f; s[8] = 0.f; }
}

// ---------------------------------------------------------------------------
// Kernel A: build per-row band images into ws.
// ws layout: ws[row*480 + (z*5 + dr)*32 + cx], row = global row 0..20479,
// z = col-block index (t-1+z), dr = grid-row offset (ry-2+dr), cx = grid col.
// One block per G=8 rows; phases 0-2 identical to the R2 fused kernel; the
// LDS band [j][3][5][32] is CONTIGUOUS with the ws row-major layout, so the
// dump is a straight 960-float4 coalesced copy.
// ---------------------------------------------------------------------------
__global__ __launch_bounds__(256) void spde_band_build(const float* __restrict__ kap,
                                                       const float* __restrict__ m,
                                                       const float* __restrict__ H,
                                                       float* __restrict__ ws) {
    const int oy[9] = {0, 0, 0, 1, -1, 1, 1, -1, -1};
    const int ox[9] = {0, 1, -1, 0, 0, 1, -1, 1, -1};

    int blk = blockIdx.x;                 // 0 .. NB*NT*(NN/G)-1 = 2559
    int b   = blk / (NT * (NN / G));
    int rem = blk - b * (NT * (NN / G));
    int t   = rem >> 7;
    int grp = rem & 127;
    int base = grp << 3;                  // first row index r of this group
    int ry = base >> 5;
    int rxb = base & 31;
    int tid = threadIdx.x;

    __shared__ float band[G * 3 * 5 * 32];    // 15360 B
    __shared__ float sk[G][9][9];
    __shared__ float moff[G][2][9];

    // ---- Phase 0/1: zero band; threads 0..87 compute the 88 stencils ----
    {
        vfloat4 z4 = {0.f, 0.f, 0.f, 0.f};
        vfloat4* p = (vfloat4*)band;          // 960 float4 slots
#pragma unroll
        for (int w = 0; w < 4; ++w) {
            int idx = tid + 256 * w;
            if (idx < (G * 3 * 5 * 32) / 4) p[idx] = z4;
        }
    }
    if (tid < G * 11) {
        int j = tid / 11, u = tid - j * 11;
        int rj = base + j;
        if (u < 9) {
            int ky = ry + c_oy[u], kx = (rxb + j) + c_ox[u];
            bool valid = ((unsigned)ky < NY) && ((unsigned)kx < NX);
            int k = valid ? (ky * NX + kx) : rj;
            float s[9];
            stencil9(kap, m, H, b, t, k, s);
#pragma unroll
            for (int e = 0; e < 9; ++e)
                sk[j][u][(oy[e] + 1) * 3 + (ox[e] + 1)] = s[e];
        } else if (u == 9) {
            float s[9] = {0, 0, 0, 0, 0, 0, 0, 0, 0};
            if (t >= 1) stencil9(kap, m, H, b, t - 1, rj, s);
#pragma unroll
            for (int e = 0; e < 9; ++e) moff[j][0][e] = -s[e];
        } else {
            float s[9] = {0, 0, 0, 0, 0, 0, 0, 0, 0};
            if (t <= NT - 2) stencil9(kap, m, H, b, t + 1, rj, s);
#pragma unroll
            for (int e = 0; e < 9; ++e) moff[j][1][e] = -s[e];
        }
    }
    __syncthreads();

    // ---- Phase 2: scatter the 8*43 nonzero entries into the band image ----
    for (int it = tid; it < G * 43; it += 256) {
        int j = it / 43, q = it - j * 43;
        int rxj = rxb + j;
        if (q < 25) {
            int dy = q / 5 - 2, dx = q % 5 - 2;
            float a = 0.f;
#pragma unroll
            for (int d1 = 0; d1 < 9; ++d1) {
                int dy2 = dy - oy[d1], dx2 = dx - ox[d1];
                if (dy2 >= -1 && dy2 <= 1 && dx2 >= -1 && dx2 <= 1) {
                    a += sk[j][0][(oy[d1] + 1) * 3 + (ox[d1] + 1)]
                       * sk[j][d1][(dy2 + 1) * 3 + (dx2 + 1)];
                }
            }
            if (q == 12 && t >= 1 && t <= NT - 2) a += 1.0f;  // MM + I interior
            int cy = ry + dy, cx = rxj + dx;
            if ((unsigned)cy < NY && (unsigned)cx < NX)
                band[((j * 3 + 1) * 5 + (dy + 2)) * 32 + cx] = a;
        } else if (q < 34) {
            int d = q - 25;
            int cy = ry + c_oy[d], cx = rxj + c_ox[d];
            if ((unsigned)cy < NY && (unsigned)cx < NX)
                band[((j * 3 + 0) * 5 + (c_oy[d] + 2)) * 32 + cx] = moff[j][0][d];
        } else {
            int d = q - 34;
            int cy = ry + c_oy[d], cx = rxj + c_ox[d];
            if ((unsigned)cy < NY && (unsigned)cx < NX)
                band[((j * 3 + 2) * 5 + (c_oy[d] + 2)) * 32 + cx] = moff[j][1][d];
        }
    }
    __syncthreads();

    // ---- Phase 3': contiguous dump of the band block to ws ----
    {
        size_t rowbase = (size_t)((b * NT + t) * NN + base);  // global row
        vfloat4* dst = (vfloat4*)(ws + rowbase * 480);
        const vfloat4* src = (const vfloat4*)band;
#pragma unroll
        for (int w = 0; w < 4; ++w) {
            int idx = tid + 256 * w;
            if (idx < 960) dst[idx] = src[idx];
        }
    }
}

// ---------------------------------------------------------------------------
// Kernel B: fill-shaped streamer. Linear grid-stride over all 26,214,400
// output float4s; ~91% of lanes store pure zeros (no load dependency); in-band
// lanes read one float4 from ws (39 MB, read ~once, L2/MALL-resident).
// This is deliberately as close as possible to rocclr fillBufferAligned,
// the only kernel measured at 6.27 TB/s on this buffer.
// ---------------------------------------------------------------------------
__global__ __launch_bounds__(256) void spde_stream(const float* __restrict__ ws,
                                                   float* __restrict__ Q) {
    const unsigned total4 = (unsigned)NB * QDIM * (QDIM / 4);  // 26,214,400
    unsigned p = blockIdx.x * 256u + threadIdx.x;
    const unsigned stride = gridDim.x * 256u;
    const vfloat4 z4 = {0.f, 0.f, 0.f, 0.f};
    const vfloat4* ws4 = (const vfloat4*)ws;
    vfloat4* Q4 = (vfloat4*)Q;
    for (; p < total4; p += stride) {
        unsigned row  = p / 1280u;            // global row 0..20479 (magic mul)
        unsigned col4 = p - row * 1280u;      // float4 col 0..1279
        int t  = (int)((row >> 10) % 5u);     // time index of this row
        int ry = (int)((row >> 5) & 31u);     // grid-row of this row
        int kk = (int)(col4 >> 8);            // column block 0..4 (wave-uniform)
        int c4 = (int)(col4 & 255u);
        int cy = c4 >> 3, cxq = c4 & 7;
        int z  = kk - t + 1;                  // band block index, wave-uniform
        int dy = cy - ry + 2;                 // band row index + 2
        vfloat4 v = z4;
        if ((unsigned)z < 3u) {               // wave-uniform branch
            int dc = min(max(dy, 0), 4);      // clamp -> always-valid load
            vfloat4 w = ws4[(size_t)row * 120 + (z * 5 + dc) * 8 + cxq];
            v = ((unsigned)dy < 5u) ? w : z4; // exact zero outside band
        }
        Q4[p] = v;
    }
}

extern "C" void kernel_launch(void* const* d_in, const int* in_sizes, int n_in,
                              void* d_out, int out_size, void* d_ws, size_t ws_size,
                              hipStream_t stream) {
    const float* kap = (const float*)d_in[0];
    const float* m   = (const float*)d_in[1];
    const float* H   = (const float*)d_in[2];
    float* Q = (float*)d_out;

    const size_t ws_needed = (size_t)NB * NT * NN * 480 * sizeof(float); // 39.3 MB
    if (d_ws != nullptr && ws_size >= ws_needed) {
        float* ws = (float*)d_ws;
        int nblocks = NB * NT * (NN / G);  // 2560
        spde_band_build<<<nblocks, 256, 0, stream>>>(kap, m, H, ws);
        spde_stream<<<4096, 256, 0, stream>>>(ws, Q);
    } else {
        // Fallback: R2 fused path unavailable here; emulate with build+stream
        // is impossible without ws, so do the trivially-correct dense variant:
        // (this branch is not expected to be taken on the harness)
        int nblocks = NB * NT * (NN / G);
        spde_band_build<<<nblocks, 256, 0, stream>>>(kap, m, H, (float*)d_out);
        // NOTE: without ws we cannot split; overwrite below regenerates Q.
        spde_stream<<<4096, 256, 0, stream>>>((const float*)d_out, Q);
    }
}

// Round 4
// 365.324 us; speedup vs baseline: 1.2331x; 1.2331x over previous
//
#include <hip/hip_runtime.h>

// Problem constants (from reference): N_T=5, 32x32 grid, N=1024, batch=4.
#define NT   5
#define NY   32
#define NX   32
#define NN   1024          // N = NY*NX
#define QDIM 5120          // NT * NN
#define NB   4
#define G    8             // rows per block (all share the same ry band)

typedef float vfloat4 __attribute__((ext_vector_type(4)));

// Canonical stencil offset order (matches reference's offs list):
// 0:(0,0) 1:(0,1) 2:(0,-1) 3:(1,0) 4:(-1,0) 5:(1,1) 6:(1,-1) 7:(-1,1) 8:(-1,-1)
__device__ const int c_oy[9] = {0, 0, 0, 1, -1, 1, 1, -1, -1};
__device__ const int c_ox[9] = {0, 1, -1, 0, 0, 1, -1, 1, -1};

// Stencil coefficients of M = I + A for node n, time t, batch b.
// Out-of-grid neighbor coefficients zeroed (matches VALID in reference).
__device__ __forceinline__ void stencil9(const float* __restrict__ kap,
                                         const float* __restrict__ m,
                                         const float* __restrict__ H,
                                         int b, int t, int n, float s[9]) {
    // Layouts: kappa (NB,1,NN,NT); m (NB,2,NN,NT); H (NB,2,2,NN,NT)
    float k   = kap[((size_t)b * NN + n) * NT + t];
    float mx  = m[(((size_t)b * 2 + 0) * NN + n) * NT + t];
    float my  = m[(((size_t)b * 2 + 1) * NN + n) * NT + t];
    float H11 = H[((((size_t)b * 2 + 0) * 2 + 0) * NN + n) * NT + t];
    float H01 = H[((((size_t)b * 2 + 0) * 2 + 1) * NN + n) * NT + t];
    float H10 = H[((((size_t)b * 2 + 1) * 2 + 0) * NN + n) * NT + t];
    float H22 = H[((((size_t)b * 2 + 1) * 2 + 1) * NN + n) * NT + t];
    float cc = 0.25f * (H01 + H10);                  // H12/(2 DX DY), DX=DY=1
    s[0] = 1.0f + k * k + 2.0f * H11 + 2.0f * H22;   // diag of M = 1 + c0
    s[1] =  0.5f * mx - H11;    // (0,+1)
    s[2] = -0.5f * mx - H11;    // (0,-1)
    s[3] =  0.5f * my - H22;    // (+1,0)
    s[4] = -0.5f * my - H22;    // (-1,0)
    s[5] = -cc;                 // (+1,+1)
    s[6] =  cc;                 // (+1,-1)
    s[7] =  cc;                 // (-1,+1)
    s[8] = -cc;                 // (-1,-1)
    int y = n >> 5, x = n & 31;
    if (x == NX - 1) { s[1] = 0.f; s[5] = 0.f; s[7] = 0.f; }
    if (x == 0)      { s[2] = 0.f; s[6] = 0.f; s[8] = 0.f; }
    if (y == NY - 1) { s[3] = 0.f; s[5] = 0.f; s[6] = 0.f; }
    if (y == 0)      { s[4] = 0.f; s[7] = 0.f; s[8] = 0.f; }
}

// R4: hipMemsetAsync zeroes all of Q at the rocclr-fill rate (the only path
// proven at 6.27 TB/s on this buffer); this kernel then writes ONLY the
// nonzero band: per row, up to 3 col-blocks x 5 grid-rows x 128 B = 15
// full-cacheline segments (39.3 MB total, coalesced ~640 B runs).
// Phases 0-2 are identical to the verified R1/R2/R3 builders.
__global__ __launch_bounds__(256) void spde_band_sparse(const float* __restrict__ kap,
                                                        const float* __restrict__ m,
                                                        const float* __restrict__ H,
                                                        float* __restrict__ Q) {
    const int oy[9] = {0, 0, 0, 1, -1, 1, 1, -1, -1};
    const int ox[9] = {0, 1, -1, 0, 0, 1, -1, 1, -1};

    int blk = blockIdx.x;                 // 0 .. NB*NT*(NN/G)-1 = 2559
    int b   = blk / (NT * (NN / G));
    int rem = blk - b * (NT * (NN / G));
    int t   = rem >> 7;                   // / (NN/G) = /128
    int grp = rem & 127;
    int base = grp << 3;                  // first row index r of this group
    int ry = base >> 5;                   // same for all 8 rows (8 | base)
    int rxb = base & 31;                  // x of row j is rxb + j (< 32)
    int tid = threadIdx.x;

    // band[((j*3 + z)*5 + dr)*32 + cx]: value of Q[row base+j, col-block
    // (t-1+z), grid-row (ry-2+dr), grid-col cx]. Rows outside band are 0.
    __shared__ float band[G * 3 * 5 * 32];    // 15360 B
    __shared__ float sk[G][9][9];    // stencil of M[t] at 9 neighbors, per row
    __shared__ float moff[G][2][9];  // -M[t-1][r,:], -M[t+1][r,:], per row

    // ---- Phase 0/1: zero band; threads 0..87 compute the 88 stencils ----
    {
        vfloat4 z4 = {0.f, 0.f, 0.f, 0.f};
        vfloat4* p = (vfloat4*)band;          // 960 float4 slots
#pragma unroll
        for (int w = 0; w < 4; ++w) {
            int idx = tid + 256 * w;
            if (idx < (G * 3 * 5 * 32) / 4) p[idx] = z4;
        }
    }
    if (tid < G * 11) {
        int j = tid / 11, u = tid - j * 11;
        int rj = base + j;
        if (u < 9) {
            int ky = ry + c_oy[u], kx = (rxb + j) + c_ox[u];
            bool valid = ((unsigned)ky < NY) && ((unsigned)kx < NX);
            int k = valid ? (ky * NX + kx) : rj;  // clamp; killed by sk[j][0]==0
            float s[9];
            stencil9(kap, m, H, b, t, k, s);
#pragma unroll
            for (int e = 0; e < 9; ++e)
                sk[j][u][(oy[e] + 1) * 3 + (ox[e] + 1)] = s[e];
        } else if (u == 9) {
            float s[9] = {0, 0, 0, 0, 0, 0, 0, 0, 0};
            if (t >= 1) stencil9(kap, m, H, b, t - 1, rj, s);
#pragma unroll
            for (int e = 0; e < 9; ++e) moff[j][0][e] = -s[e];
        } else {
            float s[9] = {0, 0, 0, 0, 0, 0, 0, 0, 0};
            if (t <= NT - 2) stencil9(kap, m, H, b, t + 1, rj, s);
#pragma unroll
            for (int e = 0; e < 9; ++e) moff[j][1][e] = -s[e];
        }
    }
    __syncthreads();

    // ---- Phase 2: scatter the 8*43 nonzero entries into the band image ----
    for (int it = tid; it < G * 43; it += 256) {
        int j = it / 43, q = it - j * 43;
        int rxj = rxb + j;
        if (q < 25) {
            // Diag block (z=1): entry (dy,dx) of row r of MM[t] (+I interior)
            int dy = q / 5 - 2, dx = q % 5 - 2;
            float a = 0.f;
#pragma unroll
            for (int d1 = 0; d1 < 9; ++d1) {
                int dy2 = dy - oy[d1], dx2 = dx - ox[d1];
                if (dy2 >= -1 && dy2 <= 1 && dx2 >= -1 && dx2 <= 1) {
                    a += sk[j][0][(oy[d1] + 1) * 3 + (ox[d1] + 1)]
                       * sk[j][d1][(dy2 + 1) * 3 + (dx2 + 1)];
                }
            }
            if (q == 12 && t >= 1 && t <= NT - 2) a += 1.0f;  // MM + I interior
            int cy = ry + dy, cx = rxj + dx;
            if ((unsigned)cy < NY && (unsigned)cx < NX)
                band[((j * 3 + 1) * 5 + (dy + 2)) * 32 + cx] = a;
        } else if (q < 34) {
            // Block t-1 (z=0): -M[t-1][r, c]; moff[j][0] is all-zero when t==0
            int d = q - 25;
            int cy = ry + c_oy[d], cx = rxj + c_ox[d];
            if ((unsigned)cy < NY && (unsigned)cx < NX)
                band[((j * 3 + 0) * 5 + (c_oy[d] + 2)) * 32 + cx] = moff[j][0][d];
        } else {
            // Block t+1 (z=2): -M[t+1][r, c]; all-zero when t==NT-1
            int d = q - 34;
            int cy = ry + c_oy[d], cx = rxj + c_ox[d];
            if ((unsigned)cy < NY && (unsigned)cx < NX)
                band[((j * 3 + 2) * 5 + (c_oy[d] + 2)) * 32 + cx] = moff[j][1][d];
        }
    }
    __syncthreads();

    // ---- Phase 3: sparse write of the band segments only ----
    // 960 float4 slots per block; consecutive idx -> contiguous LDS reads
    // (2-way bank alias, free) and contiguous 640 B global runs per (j,z).
#pragma unroll
    for (int w = 0; w < 4; ++w) {
        int idx = tid + 256 * w;
        if (idx < 960) {
            int j   = idx / 120;          // row in group       0..7
            int rm  = idx - j * 120;      //                    0..119
            int z   = rm / 40;            // col-block slot     0..2
            int rm2 = rm - z * 40;        //                    0..39
            int dr  = rm2 >> 3;           // band grid-row      0..4
            int cxq = rm2 & 7;            // float4 within row  0..7
            int kk = t - 1 + z;           // actual column block
            int cy = ry - 2 + dr;         // actual grid-row
            if ((unsigned)kk < (unsigned)NT && (unsigned)cy < (unsigned)NY) {
                vfloat4 v = *(const vfloat4*)&band[((j * 3 + z) * 5 + dr) * 32 + cxq * 4];
                size_t off = ((size_t)b * QDIM + (size_t)t * NN + base + j) * QDIM
                           + (size_t)kk * NN + cy * 32 + cxq * 4;
                *(vfloat4*)(Q + off) = v;
            }
        }
    }
}

extern "C" void kernel_launch(void* const* d_in, const int* in_sizes, int n_in,
                              void* d_out, int out_size, void* d_ws, size_t ws_size,
                              hipStream_t stream) {
    const float* kap = (const float*)d_in[0];
    const float* m   = (const float*)d_in[1];
    const float* H   = (const float*)d_in[2];
    float* Q = (float*)d_out;

    // Bulk zero via the runtime fill kernel (proven 6.27 TB/s on this buffer).
    // Async on the provided stream -> graph-capturable (same op the harness's
    // own reset() uses).
    hipMemsetAsync(d_out, 0, (size_t)out_size, stream);

    int nblocks = NB * NT * (NN / G);  // 2560 blocks, 8 rows each
    spde_band_sparse<<<nblocks, 256, 0, stream>>>(kap, m, H, Q);
}

// Round 5
// 364.842 us; speedup vs baseline: 1.2348x; 1.0013x over previous
//
#include <hip/hip_runtime.h>

// Problem constants (from reference): N_T=5, 32x32 grid, N=1024, batch=4.
#define NT   5
#define NY   32
#define NX   32
#define NN   1024          // N = NY*NX
#define QDIM 5120          // NT * NN
#define NB   4
#define G    8             // rows per block (all share the same ry band)

typedef float vfloat4 __attribute__((ext_vector_type(4)));

// Canonical stencil offset order (matches reference's offs list):
// 0:(0,0) 1:(0,1) 2:(0,-1) 3:(1,0) 4:(-1,0) 5:(1,1) 6:(1,-1) 7:(-1,1) 8:(-1,-1)
__device__ const int c_oy[9] = {0, 0, 0, 1, -1, 1, 1, -1, -1};
__device__ const int c_ox[9] = {0, 1, -1, 0, 0, 1, -1, 1, -1};

// Stencil coefficients of M = I + A for node n, time t, batch b.
// Out-of-grid neighbor coefficients zeroed (matches VALID in reference).
__device__ __forceinline__ void stencil9(const float* __restrict__ kap,
                                         const float* __restrict__ m,
                                         const float* __restrict__ H,
                                         int b, int t, int n, float s[9]) {
    // Layouts: kappa (NB,1,NN,NT); m (NB,2,NN,NT); H (NB,2,2,NN,NT)
    float k   = kap[((size_t)b * NN + n) * NT + t];
    float mx  = m[(((size_t)b * 2 + 0) * NN + n) * NT + t];
    float my  = m[(((size_t)b * 2 + 1) * NN + n) * NT + t];
    float H11 = H[((((size_t)b * 2 + 0) * 2 + 0) * NN + n) * NT + t];
    float H01 = H[((((size_t)b * 2 + 0) * 2 + 1) * NN + n) * NT + t];
    float H10 = H[((((size_t)b * 2 + 1) * 2 + 0) * NN + n) * NT + t];
    float H22 = H[((((size_t)b * 2 + 1) * 2 + 1) * NN + n) * NT + t];
    float cc = 0.25f * (H01 + H10);                  // H12/(2 DX DY), DX=DY=1
    s[0] = 1.0f + k * k + 2.0f * H11 + 2.0f * H22;   // diag of M = 1 + c0
    s[1] =  0.5f * mx - H11;    // (0,+1)
    s[2] = -0.5f * mx - H11;    // (0,-1)
    s[3] =  0.5f * my - H22;    // (+1,0)
    s[4] = -0.5f * my - H22;    // (-1,0)
    s[5] = -cc;                 // (+1,+1)
    s[6] =  cc;                 // (+1,-1)
    s[7] =  cc;                 // (-1,+1)
    s[8] = -cc;                 // (-1,-1)
    int y = n >> 5, x = n & 31;
    if (x == NX - 1) { s[1] = 0.f; s[5] = 0.f; s[7] = 0.f; }
    if (x == 0)      { s[2] = 0.f; s[6] = 0.f; s[8] = 0.f; }
    if (y == NY - 1) { s[3] = 0.f; s[5] = 0.f; s[6] = 0.f; }
    if (y == 0)      { s[4] = 0.f; s[7] = 0.f; s[8] = 0.f; }
}

// R5: lean band kernel. hipMemsetAsync (proven ~6.3 TB/s) zeroes Q; this
// kernel writes only the nonzero band segments. vs R4: the 15 KB LDS band
// image (zeroed, scattered, re-read) is GONE — phase 2 results live in tiny
// LDS tables (diag[8][25], moffg[8][2][9], ~4 KB) and phase 3 computes each
// output float4 directly from them. Phases 1-2 math is verbatim from the
// verified R1-R4 builders.
__global__ __launch_bounds__(256) void spde_band_lean(const float* __restrict__ kap,
                                                      const float* __restrict__ m,
                                                      const float* __restrict__ H,
                                                      float* __restrict__ Q) {
    const int oy[9] = {0, 0, 0, 1, -1, 1, 1, -1, -1};
    const int ox[9] = {0, 1, -1, 0, 0, 1, -1, 1, -1};

    int blk = blockIdx.x;                 // 0 .. NB*NT*(NN/G)-1 = 2559
    int b   = blk / (NT * (NN / G));
    int rem = blk - b * (NT * (NN / G));
    int t   = rem >> 7;                   // / (NN/G) = /128
    int grp = rem & 127;
    int base = grp << 3;                  // first row index r of this group
    int ry = base >> 5;                   // same for all 8 rows (8 | base)
    int rxb = base & 31;                  // x of row j is rxb + j (< 32)
    int tid = threadIdx.x;

    __shared__ float sk[G][9][9];     // stencil of M[t] at 9 neighbors, per row
    __shared__ float diag[G][25];     // row r of MM[t] (+I interior), 5x5 grid
    __shared__ float moffg[G][2][9];  // -M[t-1][r,:], -M[t+1][r,:] on 3x3 grid

    // ---- Phase 1: threads 0..87 compute the 88 stencils ----
    if (tid < G * 11) {
        int j = tid / 11, u = tid - j * 11;
        int rj = base + j;
        if (u < 9) {
            int ky = ry + c_oy[u], kx = (rxb + j) + c_ox[u];
            bool valid = ((unsigned)ky < NY) && ((unsigned)kx < NX);
            int k = valid ? (ky * NX + kx) : rj;  // clamp; killed by sk[j][0]==0
            float s[9];
            stencil9(kap, m, H, b, t, k, s);
#pragma unroll
            for (int e = 0; e < 9; ++e)
                sk[j][u][(oy[e] + 1) * 3 + (ox[e] + 1)] = s[e];
        } else if (u == 9) {
            float s[9] = {0, 0, 0, 0, 0, 0, 0, 0, 0};
            if (t >= 1) stencil9(kap, m, H, b, t - 1, rj, s);
#pragma unroll
            for (int e = 0; e < 9; ++e)
                moffg[j][0][(c_oy[e] + 1) * 3 + (c_ox[e] + 1)] = -s[e];
        } else {
            float s[9] = {0, 0, 0, 0, 0, 0, 0, 0, 0};
            if (t <= NT - 2) stencil9(kap, m, H, b, t + 1, rj, s);
#pragma unroll
            for (int e = 0; e < 9; ++e)
                moffg[j][1][(c_oy[e] + 1) * 3 + (c_ox[e] + 1)] = -s[e];
        }
    }
    __syncthreads();

    // ---- Phase 2: threads 0..199 compute the 8x25 diag-block entries ----
    if (tid < G * 25) {
        int j = tid / 25, q = tid - j * 25;
        int dy = q / 5 - 2, dx = q % 5 - 2;
        float a = 0.f;
#pragma unroll
        for (int d1 = 0; d1 < 9; ++d1) {
            int dy2 = dy - oy[d1], dx2 = dx - ox[d1];
            if (dy2 >= -1 && dy2 <= 1 && dx2 >= -1 && dx2 <= 1) {
                a += sk[j][0][(oy[d1] + 1) * 3 + (ox[d1] + 1)]
                   * sk[j][d1][(dy2 + 1) * 3 + (dx2 + 1)];
            }
        }
        if (q == 12 && t >= 1 && t <= NT - 2) a += 1.0f;  // MM + I, interior t
        diag[j][q] = a;
    }
    __syncthreads();

    // ---- Phase 3: compute + store the band segments directly ----
    // 960 float4 slots: (j row-in-group, z col-block slot, dr band grid-row,
    // cxq float4-within-row). Values come from the tiny LDS tables.
#pragma unroll
    for (int w = 0; w < 4; ++w) {
        int idx = tid + 256 * w;
        if (idx < 960) {
            int j   = idx / 120;          // 0..7
            int rm  = idx - j * 120;      // 0..119
            int z   = rm / 40;            // 0..2
            int rm2 = rm - z * 40;        // 0..39
            int dr  = rm2 >> 3;           // 0..4
            int cxq = rm2 & 7;            // 0..7
            int kk = t - 1 + z;           // actual column block
            int cy = ry - 2 + dr;         // actual grid-row
            if ((unsigned)kk < (unsigned)NT && (unsigned)cy < (unsigned)NY) {
                int rxj = rxb + j;
                int dy = dr - 2;
                vfloat4 v;
#pragma unroll
                for (int e = 0; e < 4; ++e) {
                    int cx = cxq * 4 + e;
                    int dx = cx - rxj;
                    float val = 0.f;
                    if (z == 1) {
                        if (dx >= -2 && dx <= 2)
                            val = diag[j][dr * 5 + (dx + 2)];
                    } else {
                        if (dy >= -1 && dy <= 1 && dx >= -1 && dx <= 1)
                            val = moffg[j][z >> 1][(dy + 1) * 3 + (dx + 1)];
                    }
                    v[e] = val;
                }
                size_t off = ((size_t)b * QDIM + (size_t)t * NN + base + j) * QDIM
                           + (size_t)kk * NN + cy * 32 + cxq * 4;
                *(vfloat4*)(Q + off) = v;
            }
        }
    }
}

extern "C" void kernel_launch(void* const* d_in, const int* in_sizes, int n_in,
                              void* d_out, int out_size, void* d_ws, size_t ws_size,
                              hipStream_t stream) {
    const float* kap = (const float*)d_in[0];
    const float* m   = (const float*)d_in[1];
    const float* H   = (const float*)d_in[2];
    float* Q = (float*)d_out;

    // Bulk zero via the runtime fill path (proven ~6.3 TB/s on this device).
    hipMemsetAsync(d_out, 0, (size_t)out_size, stream);

    int nblocks = NB * NT * (NN / G);  // 2560 blocks, 8 rows each
    spde_band_lean<<<nblocks, 256, 0, stream>>>(kap, m, H, Q);
}